// Round 8
// baseline (879.712 us; speedup 1.0000x reference)
//
#include <hip/hip_runtime.h>
#include <cstdint>
#include <cstddef>

// ---------------------------------------------------------------------------
// KascadeAnchorAttention: x->QKV proj (+RoPE) -> causal attn -> out proj,
// plus top-8 tile indices from rep-row logits.
// B=2 H=16 S=2048 Dh=128 D=2048. TILE=128 TOPK=8.
//
// R6 -> R7 (attention only):
//  - double-buffered K/V staging, counted s_waitcnt vmcnt(8) + raw s_barrier
//    (2 barriers/iter, loads stay in flight across barriers = T3/T4-lite)
//  - single wave-private sP (mid-iter barrier removed)
//  - O-store coalesced via LDS staging (fix 4.8x write amplification)
// ---------------------------------------------------------------------------

#define S_LEN 2048
#define NH 16
#define DHD 128
#define DMODEL 2048
#define MROWS 4096
#define SCALE 0.08838834764831845f   // 1/sqrt(128)
#define SCALE_L2E (0.08838834764831845f * 1.4426950408889634f)
#define NEG10 -1e10f

typedef short short8 __attribute__((ext_vector_type(8)));
typedef __bf16 bf16x8 __attribute__((ext_vector_type(8)));
typedef float f32x4 __attribute__((ext_vector_type(4)));

#define MFMA16(a, b, c) __builtin_amdgcn_mfma_f32_16x16x32_bf16((a), (b), (c), 0, 0, 0)

__device__ __forceinline__ void gl16(const void* g, void* s) {
  __builtin_amdgcn_global_load_lds(
      (const __attribute__((address_space(1))) void*)g,
      (__attribute__((address_space(3))) void*)s, 16, 0, 0);
}

__device__ __forceinline__ unsigned short f2bf(float f) {
  unsigned u = __float_as_uint(f);
  return (unsigned short)((u + 0x7fffu + ((u >> 16) & 1u)) >> 16);  // RNE
}
__device__ __forceinline__ float bf2f(unsigned short h) {
  return __uint_as_float(((unsigned)h) << 16);
}

// ---------------- split x into bf16 hi/lo ----------------
__global__ __launch_bounds__(256) void k_split_x(const float* __restrict__ x,
                                                 unsigned short* __restrict__ xh,
                                                 unsigned short* __restrict__ xl, int n4) {
  int i = blockIdx.x * blockDim.x + threadIdx.x;
  for (; i < n4; i += gridDim.x * blockDim.x) {
    float4 v = ((const float4*)x)[i];
    float f[4] = {v.x, v.y, v.z, v.w};
    unsigned short hh[4], ll[4];
#pragma unroll
    for (int j = 0; j < 4; j++) {
      hh[j] = f2bf(f[j]);
      ll[j] = f2bf(f[j] - bf2f(hh[j]));
    }
    ((ushort4*)xh)[i] = make_ushort4(hh[0], hh[1], hh[2], hh[3]);
    ((ushort4*)xl)[i] = make_ushort4(ll[0], ll[1], ll[2], ll[3]);
  }
}

// ---------------- transpose weight [K][N] -> [N][K] bf16 (hi, optional lo) ---
template <int LO>
__global__ __launch_bounds__(256) void k_transw(const float* __restrict__ w,
                                                unsigned short* __restrict__ th,
                                                unsigned short* __restrict__ tl) {
  int n = blockIdx.x * 256 + threadIdx.x;
  int r0 = blockIdx.y * 32;
  float vals[32];
#pragma unroll
  for (int j = 0; j < 32; j++) vals[j] = w[(size_t)(r0 + j) * DMODEL + n];
  unsigned short hs[32];
#pragma unroll
  for (int j = 0; j < 32; j++) hs[j] = f2bf(vals[j]);
  unsigned short* dsth = th + (size_t)n * DMODEL + r0;
#pragma unroll
  for (int c = 0; c < 4; c++) {
    short8 v;
#pragma unroll
    for (int j = 0; j < 8; j++) v[j] = (short)hs[c * 8 + j];
    *(short8*)(dsth + c * 8) = v;
  }
  if (LO) {
    unsigned short ls[32];
#pragma unroll
    for (int j = 0; j < 32; j++) ls[j] = f2bf(vals[j] - bf2f(hs[j]));
    unsigned short* dstl = tl + (size_t)n * DMODEL + r0;
#pragma unroll
    for (int c = 0; c < 4; c++) {
      short8 v;
#pragma unroll
      for (int j = 0; j < 8; j++) v[j] = (short)ls[c * 8 + j];
      *(short8*)(dstl + c * 8) = v;
    }
  }
}

// ---------------- 128x128 MFMA GEMM, BK=32, optional bf16x2 split ----------
template <int SPLIT, int EPI>
__global__ __launch_bounds__(256) void k_gemm(const unsigned short* __restrict__ A,
                                              const unsigned short* __restrict__ Al,
                                              const unsigned short* __restrict__ Bt,
                                              const unsigned short* __restrict__ Btl,
                                              void* __restrict__ outp) {
  constexpr int NSM = (SPLIT ? 4 : 2) * 4096;
  __shared__ unsigned short sm[NSM];
  unsigned short* sAh = sm;
  unsigned short* sAl = SPLIT ? (sm + 4096) : nullptr;
  unsigned short* sBh = sm + (SPLIT ? 8192 : 4096);
  unsigned short* sBl = SPLIT ? (sm + 12288) : nullptr;

  const int tid = threadIdx.x;
  const int l = tid & 63, w = tid >> 6;
  const int lr = l & 15, lk = l >> 4;
  const int rowBase = blockIdx.y * 128;
  const int colBase = blockIdx.x * 128;
  const int wr = (w >> 1) * 64, wc = (w & 1) * 64;

  f32x4 zero = {0.f, 0.f, 0.f, 0.f};
  f32x4 acc[4][4];
#pragma unroll
  for (int mi = 0; mi < 4; mi++)
#pragma unroll
    for (int ni = 0; ni < 4; ni++) acc[mi][ni] = zero;

  for (int kt = 0; kt < 64; ++kt) {
#pragma unroll
    for (int p = 0; p < 2; ++p) {
      int c = w * 128 + p * 64 + l;
      int row = c >> 2, sl = c & 3;
      int kbl = sl ^ ((row >> 1) & 3);
      size_t srca = (size_t)(rowBase + row) * DMODEL + kt * 32 + kbl * 8;
      gl16(A + srca, (char*)sAh + c * 16);
      if (SPLIT) gl16(Al + srca, (char*)sAl + c * 16);
      size_t srcb = (size_t)(colBase + row) * DMODEL + kt * 32 + kbl * 8;
      gl16(Bt + srcb, (char*)sBh + c * 16);
      if (SPLIT) gl16(Btl + srcb, (char*)sBl + c * 16);
    }
    __syncthreads();

    bf16x8 ah[4], alo[4], bh[4], blo[4];
#pragma unroll
    for (int mi = 0; mi < 4; mi++) {
      int row = wr + mi * 16 + lr;
      int off = row * 32 + ((lk ^ ((row >> 1) & 3)) * 8);
      ah[mi] = *(const bf16x8*)(sAh + off);
      if (SPLIT) alo[mi] = *(const bf16x8*)(sAl + off);
    }
#pragma unroll
    for (int ni = 0; ni < 4; ni++) {
      int row = wc + ni * 16 + lr;
      int off = row * 32 + ((lk ^ ((row >> 1) & 3)) * 8);
      bh[ni] = *(const bf16x8*)(sBh + off);
      if (SPLIT) blo[ni] = *(const bf16x8*)(sBl + off);
    }
#pragma unroll
    for (int mi = 0; mi < 4; mi++)
#pragma unroll
      for (int ni = 0; ni < 4; ni++) {
        acc[mi][ni] = MFMA16(ah[mi], bh[ni], acc[mi][ni]);
        if (SPLIT) {
          acc[mi][ni] = MFMA16(alo[mi], bh[ni], acc[mi][ni]);
          acc[mi][ni] = MFMA16(ah[mi], blo[ni], acc[mi][ni]);
        }
      }
    __syncthreads();
  }

#pragma unroll
  for (int mi = 0; mi < 4; mi++)
#pragma unroll
    for (int ni = 0; ni < 4; ni++)
#pragma unroll
      for (int r = 0; r < 4; r++) {
        int row = rowBase + wr + mi * 16 + lk * 4 + r;
        int col = colBase + wc + ni * 16 + lr;
        float v = acc[mi][ni][r];
        if (EPI == 2) {
          ((float*)outp)[(size_t)row * DMODEL + col] = v;
        } else {
          size_t idx = (((size_t)(row >> 11) * NH + (col >> 7)) * S_LEN + (row & 2047)) * DHD +
                       (col & 127);
          if (EPI == 1)
            ((float*)outp)[idx] = v;
          else
            ((unsigned short*)outp)[idx] = f2bf(v);
        }
      }
}

// ---------------- RoPE, half-split form -------------------------------------
__global__ __launch_bounds__(256) void k_rope_q(unsigned short* __restrict__ q,
                                                const float* __restrict__ cosT,
                                                const float* __restrict__ sinT) {
  int t = blockIdx.x * blockDim.x + threadIdx.x;
  int row = t >> 4;
  int i4 = (t & 15) * 4;
  int s = row & 2047;
  unsigned short* p0 = q + (size_t)row * DHD + i4;
  unsigned short* p1 = p0 + 64;
  ushort4 a = *(ushort4*)p0, b = *(ushort4*)p1;
  float4 c = *(const float4*)(cosT + (size_t)s * 64 + i4);
  float4 sn = *(const float4*)(sinT + (size_t)s * 64 + i4);
  float av[4] = {bf2f(a.x), bf2f(a.y), bf2f(a.z), bf2f(a.w)};
  float bv[4] = {bf2f(b.x), bf2f(b.y), bf2f(b.z), bf2f(b.w)};
  float cv[4] = {c.x, c.y, c.z, c.w}, sv[4] = {sn.x, sn.y, sn.z, sn.w};
  unsigned short na[4], nb[4];
#pragma unroll
  for (int j = 0; j < 4; j++) {
    na[j] = f2bf(av[j] * cv[j] - bv[j] * sv[j]);
    nb[j] = f2bf(bv[j] * cv[j] + av[j] * sv[j]);
  }
  *(ushort4*)p0 = make_ushort4(na[0], na[1], na[2], na[3]);
  *(ushort4*)p1 = make_ushort4(nb[0], nb[1], nb[2], nb[3]);
}

__global__ __launch_bounds__(256) void k_rope_k(float* __restrict__ kf,
                                                unsigned short* __restrict__ kb,
                                                const float* __restrict__ cosT,
                                                const float* __restrict__ sinT) {
  int t = blockIdx.x * blockDim.x + threadIdx.x;
  int row = t >> 4;
  int i4 = (t & 15) * 4;
  int s = row & 2047;
  float* p0 = kf + (size_t)row * DHD + i4;
  float* p1 = p0 + 64;
  float4 a = *(float4*)p0, b = *(float4*)p1;
  float4 c = *(const float4*)(cosT + (size_t)s * 64 + i4);
  float4 sn = *(const float4*)(sinT + (size_t)s * 64 + i4);
  float av[4] = {a.x, a.y, a.z, a.w}, bv[4] = {b.x, b.y, b.z, b.w};
  float cv[4] = {c.x, c.y, c.z, c.w}, sv[4] = {sn.x, sn.y, sn.z, sn.w};
  float na[4], nb[4];
#pragma unroll
  for (int j = 0; j < 4; j++) {
    na[j] = av[j] * cv[j] - bv[j] * sv[j];
    nb[j] = bv[j] * cv[j] + av[j] * sv[j];
  }
  *(float4*)p0 = make_float4(na[0], na[1], na[2], na[3]);
  *(float4*)p1 = make_float4(nb[0], nb[1], nb[2], nb[3]);
  unsigned short* kb0 = kb + (size_t)row * DHD + i4;
  *(ushort4*)kb0 = make_ushort4(f2bf(na[0]), f2bf(na[1]), f2bf(na[2]), f2bf(na[3]));
  *(ushort4*)(kb0 + 64) = make_ushort4(f2bf(nb[0]), f2bf(nb[1]), f2bf(nb[2]), f2bf(nb[3]));
}

// ---------------- V transpose: [bh][S][Dh] -> [bh][Dh][S] bf16 --------------
__global__ __launch_bounds__(256) void k_vtrans(const unsigned short* __restrict__ v,
                                                unsigned short* __restrict__ vt) {
  int bh = blockIdx.y;
  int s0 = blockIdx.x * 64 + (threadIdx.x >> 7) * 32;
  int d = threadIdx.x & 127;
  unsigned short tmp[32];
#pragma unroll
  for (int j = 0; j < 32; j++) tmp[j] = v[((size_t)bh * S_LEN + s0 + j) * DHD + d];
  unsigned short* dst = vt + ((size_t)bh * DHD + d) * S_LEN + s0;
#pragma unroll
  for (int c = 0; c < 4; c++) {
    short8 x;
#pragma unroll
    for (int j = 0; j < 8; j++) x[j] = (short)tmp[c * 8 + j];
    *(short8*)(dst + c * 8) = x;
  }
}

// ---------------- flash attention helpers -----------------------------------
__device__ __forceinline__ void attn_qk_sm(const bf16x8 (&qf)[4], f32x4 (&acc)[8],
                                           float (&mrow)[4], float (&lsum)[4],
                                           const unsigned short* sK, __bf16* sP,
                                           int ktbase, bool diag, int q0, int w, int lr,
                                           int lk) {
  f32x4 zero = {0.f, 0.f, 0.f, 0.f};
  f32x4 sf[4];
#pragma unroll
  for (int nk = 0; nk < 4; nk++) {
    f32x4 sacc = zero;
#pragma unroll
    for (int kd = 0; kd < 4; kd++) {
      int row = nk * 16 + lr;
      int off = row * 128 + (((kd * 4 + lk) ^ (row & 7)) * 8);
      bf16x8 kfrag = *(const bf16x8*)(sK + off);
      sacc = MFMA16(qf[kd], kfrag, sacc);
    }
    sf[nk] = sacc;
  }
#pragma unroll
  for (int r = 0; r < 4; r++) {
    int qpos = q0 + w * 16 + lk * 4 + r;
    float lg[4];
    float mx = -3e38f;
#pragma unroll
    for (int nk = 0; nk < 4; nk++) {
      int kpos = ktbase + nk * 16 + lr;
      float vsc = sf[nk][r] * SCALE_L2E;
      if (diag && kpos > qpos) vsc = -3e38f;
      lg[nk] = vsc;
      mx = fmaxf(mx, vsc);
    }
#pragma unroll
    for (int d = 1; d < 16; d <<= 1) mx = fmaxf(mx, __shfl_xor(mx, d));
    if (mx > mrow[r]) {  // defer-rescale: exact (corr==1 path skipped entirely)
      float corr = exp2f(mrow[r] - mx);
      mrow[r] = mx;
      lsum[r] *= corr;
#pragma unroll
      for (int ni = 0; ni < 8; ni++) acc[ni][r] *= corr;
    }
    float m = mrow[r];
    float ps = 0.f;
    int prow = w * 16 + lk * 4 + r;
#pragma unroll
    for (int nk = 0; nk < 4; nk++) {
      float pv = exp2f(lg[nk] - m);
      ps += pv;
      sP[prow * 72 + nk * 16 + lr] = (__bf16)pv;
    }
    lsum[r] += ps;  // per-lane partial; reduced once at the end
  }
}

__device__ __forceinline__ void attn_pv(f32x4 (&acc)[8], const __bf16* sP,
                                        const unsigned short* sV, int w, int lr, int lk) {
  bf16x8 pa[2];
#pragma unroll
  for (int ks = 0; ks < 2; ks++) {
    int row = w * 16 + lr;
    pa[ks] = *(const bf16x8*)(sP + row * 72 + ks * 32 + lk * 8);
  }
#pragma unroll
  for (int ni = 0; ni < 8; ni++) {
#pragma unroll
    for (int ks = 0; ks < 2; ks++) {
      int row = ni * 16 + lr;
      int off = row * 64 + (((ks * 4 + lk) ^ (row & 7)) * 8);
      bf16x8 vf = *(const bf16x8*)(sV + off);
      acc[ni] = MFMA16(pa[ks], vf, acc[ni]);
    }
  }
}

// ---------------- flash attention (causal), paired q-tiles, dbuf pipeline ----
// 512 blocks; block handles q-tiles p and 31-p in ONE k-loop (shared staging).
// K/V double-buffered; counted vmcnt(8) keeps next tile's 8 loads in flight
// across raw s_barriers. sP is wave-private (no mid-iter barrier needed).
__global__ __launch_bounds__(256, 2) void k_attn(const unsigned short* __restrict__ q,
                                                 const unsigned short* __restrict__ k,
                                                 const unsigned short* __restrict__ vt,
                                                 unsigned short* __restrict__ o) {
  __shared__ unsigned short sK[2][64 * 128];  // [kp][d], 16B-slot ^= (kp&7)
  __shared__ unsigned short sV[2][128 * 64];  // [dh][kp], 16B-slot ^= (dh&7)
  __shared__ __bf16 sP[64 * 72];              // wave-private rows

  const int bid = blockIdx.x;
  const int workid = (bid & 7) * 64 + (bid >> 3);  // nwg=512, 512%8==0 -> bijective
  const int bh = workid >> 4, p = workid & 15;
  const int qtA = p, qtB = 31 - p;
  const int b = bh >> 4, h = bh & 15;
  const int tid = threadIdx.x, l = tid & 63, w = tid >> 6;
  const int lr = l & 15, lk = l >> 4;
  const int q0A = qtA * 64, q0B = qtB * 64;
  const size_t kvbase = (size_t)bh * S_LEN * DHD;

  bf16x8 qfA[4], qfB[4];
#pragma unroll
  for (int kd = 0; kd < 4; kd++) {
    qfA[kd] = *(const bf16x8*)(q + kvbase + (size_t)(q0A + w * 16 + lr) * DHD + kd * 32 + lk * 8);
    qfB[kd] = *(const bf16x8*)(q + kvbase + (size_t)(q0B + w * 16 + lr) * DHD + kd * 32 + lk * 8);
  }

  f32x4 zero = {0.f, 0.f, 0.f, 0.f};
  f32x4 accA[8], accB[8];
  float mrowA[4], lsumA[4], mrowB[4], lsumB[4];
#pragma unroll
  for (int ni = 0; ni < 8; ni++) { accA[ni] = zero; accB[ni] = zero; }
#pragma unroll
  for (int r = 0; r < 4; r++) {
    mrowA[r] = -3e38f; lsumA[r] = 0.f;
    mrowB[r] = -3e38f; lsumB[r] = 0.f;
  }

  auto stageV = [&](int kt, int buf) {
#pragma unroll
    for (int pp = 0; pp < 4; ++pp) {
      int c = pp * 256 + tid;
      int dh = c >> 3, sl = c & 7;
      int sls = sl ^ (dh & 7);
      gl16(vt + ((size_t)bh * DHD + dh) * S_LEN + kt * 64 + sls * 8, (char*)sV[buf] + c * 16);
    }
  };
  auto stageK = [&](int kt, int buf) {
#pragma unroll
    for (int pp = 0; pp < 4; ++pp) {
      int c = pp * 256 + tid;
      int kp = c >> 4, sl = c & 15;
      int sls = sl ^ (kp & 7);
      gl16(k + kvbase + (size_t)(kt * 64 + kp) * DHD + sls * 8, (char*)sK[buf] + c * 16);
    }
  };

  // prologue: tile 0 into buffer 0  (8 loads in flight)
  stageV(0, 0);
  stageK(0, 0);
  int cur = 0;

  for (int kt = 0; kt <= qtB; ++kt) {
    if (kt < qtB) {
      stageV(kt + 1, cur ^ 1);
      stageK(kt + 1, cur ^ 1);
      asm volatile("s_waitcnt vmcnt(8)" ::: "memory");  // tile kt done; kt+1 in flight
    } else {
      asm volatile("s_waitcnt vmcnt(0)" ::: "memory");
    }
    __builtin_amdgcn_s_barrier();

    const bool doA = (kt <= qtA);
    attn_qk_sm(qfB, accB, mrowB, lsumB, sK[cur], sP, kt * 64, kt == qtB, q0B, w, lr, lk);
    attn_pv(accB, sP, sV[cur], w, lr, lk);
    if (doA) {
      attn_qk_sm(qfA, accA, mrowA, lsumA, sK[cur], sP, kt * 64, kt == qtA, q0A, w, lr, lk);
      attn_pv(accA, sP, sV[cur], w, lr, lk);
    }
    __builtin_amdgcn_s_barrier();
    cur ^= 1;
  }

  // final lsum reduce (deferred from per-iter)
#pragma unroll
  for (int r = 0; r < 4; r++) {
#pragma unroll
    for (int d = 1; d < 16; d <<= 1) {
      lsumA[r] += __shfl_xor(lsumA[r], d);
      lsumB[r] += __shfl_xor(lsumB[r], d);
    }
  }

  // O-store: stage through LDS (reuse sK), write 16B/lane coalesced
  unsigned short* sO = (unsigned short*)sK;  // 64 rows x 136 elems fits in 32KB
  {
    // segment B
#pragma unroll
    for (int r = 0; r < 4; r++) {
      float inv = 1.0f / lsumB[r];
      int row = w * 16 + lk * 4 + r;
#pragma unroll
      for (int ni = 0; ni < 8; ni++) sO[row * 136 + ni * 16 + lr] = f2bf(accB[ni][r] * inv);
    }
    __syncthreads();
#pragma unroll
    for (int pass = 0; pass < 4; ++pass) {
      int idx = pass * 256 + tid;
      int row = idx >> 4, c8 = (idx & 15) * 8;
      short8 v = *(short8*)(sO + row * 136 + c8);
      *(short8*)(o + ((size_t)b * S_LEN + q0B + row) * DMODEL + h * DHD + c8) = v;
    }
    __syncthreads();
    // segment A
#pragma unroll
    for (int r = 0; r < 4; r++) {
      float inv = 1.0f / lsumA[r];
      int row = w * 16 + lk * 4 + r;
#pragma unroll
      for (int ni = 0; ni < 8; ni++) sO[row * 136 + ni * 16 + lr] = f2bf(accA[ni][r] * inv);
    }
    __syncthreads();
#pragma unroll
    for (int pass = 0; pass < 4; ++pass) {
      int idx = pass * 256 + tid;
      int row = idx >> 4, c8 = (idx & 15) * 8;
      short8 v = *(short8*)(sO + row * 136 + c8);
      *(short8*)(o + ((size_t)b * S_LEN + q0A + row) * DMODEL + h * DHD + c8) = v;
    }
  }
}

// ---------------- tile scoring + top-8 (exact ranking, fp32) ----------------
__global__ __launch_bounds__(256) void k_score(const float* __restrict__ x,
                                               const float* __restrict__ wq,
                                               const float* __restrict__ cosT,
                                               const float* __restrict__ sinT,
                                               const float* __restrict__ kf,
                                               float* __restrict__ idxout) {
  const int t = blockIdx.x, bh = blockIdx.y;
  const int b = bh >> 4, h = bh & 15;
  const int srep = t * 128 + 127;
  const int tid = threadIdx.x;
  __shared__ float qr[128];
  __shared__ float part[256];
  __shared__ unsigned keys[16];

  {
    const int dh = tid & 127, half = tid >> 7;
    const float* xrow = x + ((size_t)b * S_LEN + srep) * DMODEL;
    const float* wcol = wq + (size_t)h * DHD + dh;
    float s0 = 0.f, s1 = 0.f, s2 = 0.f, s3 = 0.f;
    const int dbase = half * 1024;
    for (int d = 0; d < 1024; d += 4) {
      int dd = dbase + d;
      s0 = fmaf(xrow[dd], wcol[(size_t)dd * DMODEL], s0);
      s1 = fmaf(xrow[dd + 1], wcol[(size_t)(dd + 1) * DMODEL], s1);
      s2 = fmaf(xrow[dd + 2], wcol[(size_t)(dd + 2) * DMODEL], s2);
      s3 = fmaf(xrow[dd + 3], wcol[(size_t)(dd + 3) * DMODEL], s3);
    }
    part[tid] = (s0 + s1) + (s2 + s3);
  }
  if (tid < 16) keys[tid] = ~__float_as_uint(NEG10);
  __syncthreads();
  if (tid < 64) {
    int i = tid;
    float q0v = part[i] + part[i + 128];
    float q1v = part[i + 64] + part[i + 192];
    float c = cosT[(size_t)srep * 64 + i], sn = sinT[(size_t)srep * 64 + i];
    qr[i] = q0v * c - q1v * sn;
    qr[i + 64] = q1v * c + q0v * sn;
  }
  __syncthreads();

  for (int j = tid; j <= srep; j += 256) {
    const float4* krow = (const float4*)(kf + ((size_t)bh * S_LEN + j) * DHD);
    float a0 = 0.f, a1 = 0.f, a2 = 0.f, a3 = 0.f;
#pragma unroll 8
    for (int d4 = 0; d4 < 32; d4++) {
      float4 kv = krow[d4];
      const float* qq = qr + d4 * 4;
      a0 = fmaf(kv.x, qq[0], a0);
      a1 = fmaf(kv.y, qq[1], a1);
      a2 = fmaf(kv.z, qq[2], a2);
      a3 = fmaf(kv.w, qq[3], a3);
    }
    float lg = ((a0 + a1) + (a2 + a3)) * SCALE;
    unsigned u = __float_as_uint(lg);
    unsigned key = (u & 0x80000000u) ? ~u : (u | 0x80000000u);
    atomicMax(&keys[j >> 7], key);
  }
  __syncthreads();

  if (tid == 0) {
    unsigned used = 0;
    float* dst = idxout + ((size_t)bh * 16 + t) * 8;
    for (int r = 0; r < 8; ++r) {
      int best = -1;
      unsigned bk = 0;
#pragma unroll
      for (int tl = 0; tl < 16; ++tl) {
        if (used & (1u << tl)) continue;
        unsigned kv = keys[tl];
        if (best < 0 || kv > bk) {
          bk = kv;
          best = tl;
        }
      }
      used |= (1u << best);
      dst[r] = (float)best;
    }
  }
}

// ---------------------------------------------------------------------------
extern "C" void kernel_launch(void* const* d_in, const int* in_sizes, int n_in,
                              void* d_out, int out_size, void* d_ws, size_t ws_size,
                              hipStream_t stream) {
  (void)in_sizes; (void)n_in; (void)out_size; (void)ws_size;
  const float* x = (const float*)d_in[0];
  const float* wq = (const float*)d_in[1];
  const float* wk = (const float*)d_in[2];
  const float* wv = (const float*)d_in[3];
  const float* wo = (const float*)d_in[4];
  const float* cosT = (const float*)d_in[5];
  const float* sinT = (const float*)d_in[6];
  float* out0 = (float*)d_out;                       // [2,2048,2048] fp32
  float* out1 = out0 + (size_t)MROWS * DMODEL;       // [2,16,16,8] indices as float
  float* kf32 = out0;                                // reuse out0 as k_f32 scratch!

  char* ws = (char*)d_ws;
  size_t off = 0;
  auto alloc = [&](size_t bytes) {
    void* p = ws + off;
    off += (bytes + 255) & ~(size_t)255;
    return p;
  };
  unsigned short* xh = (unsigned short*)alloc(16777216);
  unsigned short* xl = (unsigned short*)alloc(16777216);
  unsigned short* wqT = (unsigned short*)alloc(8388608);
  unsigned short* wkT = (unsigned short*)alloc(8388608);
  unsigned short* wkTl = (unsigned short*)alloc(8388608);
  unsigned short* wvT = (unsigned short*)alloc(8388608);
  unsigned short* woT = (unsigned short*)alloc(8388608);
  unsigned short* qbf = (unsigned short*)alloc(16777216);
  unsigned short* kbf = (unsigned short*)alloc(16777216);
  unsigned short* vbf = (unsigned short*)alloc(16777216);
  // alias dead regions: obf<-xh (xh dead after proj GEMMs), vtbf<-xl
  unsigned short* obf = xh;
  unsigned short* vtbf = xl;

  k_split_x<<<2048, 256, 0, stream>>>(x, xh, xl, MROWS * DMODEL / 4);
  dim3 gtw(8, 64);
  k_transw<0><<<gtw, 256, 0, stream>>>(wq, wqT, nullptr);
  k_transw<1><<<gtw, 256, 0, stream>>>(wk, wkT, wkTl);
  k_transw<0><<<gtw, 256, 0, stream>>>(wv, wvT, nullptr);
  k_transw<0><<<gtw, 256, 0, stream>>>(wo, woT, nullptr);

  dim3 gg(16, 32);
  k_gemm<0, 0><<<gg, 256, 0, stream>>>(xh, nullptr, wqT, nullptr, qbf);
  k_gemm<1, 1><<<gg, 256, 0, stream>>>(xh, xl, wkT, wkTl, kf32);   // fp32-grade k
  k_gemm<0, 0><<<gg, 256, 0, stream>>>(xh, nullptr, wvT, nullptr, vbf);

  k_rope_q<<<4096, 256, 0, stream>>>(qbf, cosT, sinT);
  k_rope_k<<<4096, 256, 0, stream>>>(kf32, kbf, cosT, sinT);

  k_vtrans<<<dim3(32, 32), 256, 0, stream>>>(vbf, vtbf);
  k_attn<<<512, 256, 0, stream>>>(qbf, kbf, vtbf, obf);

  // scoring must run BEFORE the final GEMM overwrites kf32 (== out0)
  k_score<<<dim3(16, 32), 256, 0, stream>>>(x, wq, cosT, sinT, kf32, out1);

  k_gemm<0, 2><<<gg, 256, 0, stream>>>(obf, nullptr, woT, nullptr, out0);
}